// Round 12
// baseline (83.575 us; speedup 1.0000x reference)
//
#include <hip/hip_runtime.h>
#include <math.h>

#define NN 128
#define FF 32
#define EG ((NN * NN) / 4)     // 4096 blocks, 4 edge-wave slots each

__device__ __forceinline__ float sig_(float v) { return 1.f / (1.f + expf(-v)); }

// acc += u4 . vec[g0..g0+3]  (vec in vector layout: lane v holds vec[v&31])
#define DOT4(acc, u4, vec, g0)                                         \
    acc += u4.x * __shfl(vec, (g0) + 0) + u4.y * __shfl(vec, (g0) + 1) \
         + u4.z * __shfl(vec, (g0) + 2) + u4.w * __shfl(vec, (g0) + 3);

// ---------------------------------------------------------------------------
// Step 0 (messages == 0). One wave per directed edge e=(i,j) (adj-probe):
//   wux = Wu[e]@x_i, wcmx = Wcm[e]@x_i  -> persisted to WUX/WCMX
//   M1[e] = sig(wux+bu) * tanh(wcmx+bcm)
//   r1 = sig(wux + Uu[e]@M1[e] + bu);  RM1[e] = r1 * M1[e]   (lookahead)
// No atomics, no accumulators. Lane l: f=l>>1, h=l&1, ll=l&31.
// ---------------------------------------------------------------------------
__global__ __launch_bounds__(256) void k_step0(
        const int* __restrict__ adj, const float* __restrict__ x,
        const float* __restrict__ Wu, const float* __restrict__ Wcm,
        const float* __restrict__ Uu,
        const float* __restrict__ bu, const float* __restrict__ bcm,
        float* __restrict__ WUX, float* __restrict__ WCMX,
        float* __restrict__ M1, float* __restrict__ RM1) {
    const int e = blockIdx.x * 4 + (threadIdx.x >> 6);
    if (!adj[e]) return;
    const int l = threadIdx.x & 63;
    const int i = e >> 7;
    const int f = l >> 1, h = l & 1, ll = l & 31;
    const float bu_f = bu[f], bcm_f = bcm[f];
    const size_t rb = ((size_t)e * FF + f) * FF + h * 16;
    const float xv = x[i * FF + ll];
    const float4* __restrict__ wp = (const float4*)(Wu + rb);
    const float4* __restrict__ cp = (const float4*)(Wcm + rb);
    float a0 = 0.f, a1 = 0.f;
#pragma unroll
    for (int q = 0; q < 4; ++q) {
        const float4 w4 = wp[q], c4 = cp[q];
        const int g0 = h * 16 + q * 4;
        DOT4(a0, w4, xv, g0)
        DOT4(a1, c4, xv, g0)
    }
    a0 += __shfl_xor(a0, 1);
    a1 += __shfl_xor(a1, 1);
    if (h == 0) {
        WUX[(size_t)e * FF + f] = a0;
        WCMX[(size_t)e * FF + f] = a1;
    }
    const float m_pair = sig_(a0 + bu_f) * tanhf(a1 + bcm_f);
    const float mv = __shfl(m_pair, 2 * ll);     // vector layout
    if (l < 32) M1[(size_t)e * FF + ll] = mv;
    const float4* __restrict__ up = (const float4*)(Uu + rb);
    float aR = 0.f;
#pragma unroll
    for (int q = 0; q < 4; ++q) {
        const float4 u4 = up[q];
        const int g0 = h * 16 + q * 4;
        DOT4(aR, u4, mv, g0)
    }
    aR += __shfl_xor(aR, 1);
    const float rm_pair = sig_(a0 + aR + bu_f) * m_pair;
    const float rmv = __shfl(rm_pair, 2 * ll);
    if (l < 32) RM1[(size_t)e * FF + ll] = rmv;
}

// ---------------------------------------------------------------------------
// Steps 1..3. One wave per edge e=(i,j). Self-contained: sin_t[i] and
// rout_t[i] are recomputed on the fly from the neighbor rows of M_in / RM_in
// (ballot on adjacency row i -> bitmask walk; lines are L2-hot since all
// deg(i) edges of node i read them). Then the GRU update + r-lookahead:
//   prev = sin - M_in[j,i];  z = sig(WUX + Uu@prev + bu)
//   rs = rout - RM_in[e];    cm = tanh(WCMX + Ucm@rs + bcm)
//   mnew = (1-z)*prev + z*cm -> M_out[e]
//   r' = sig(WUX + Uu@mnew + bu);  RM_out[e] = r'*mnew
// No atomics anywhere.
// ---------------------------------------------------------------------------
__global__ __launch_bounds__(256) void k_step(
        const int* __restrict__ adj,
        const float* __restrict__ Uu, const float* __restrict__ Ucm,
        const float* __restrict__ bu, const float* __restrict__ bcm,
        const float* __restrict__ WUX, const float* __restrict__ WCMX,
        const float* __restrict__ M_in, float* __restrict__ M_out,
        const float* __restrict__ RM_in, float* __restrict__ RM_out) {
    const int e = blockIdx.x * 4 + (threadIdx.x >> 6);
    if (!adj[e]) return;
    const int l = threadIdx.x & 63;
    const int i = e >> 7, j = e & 127;
    const int f = l >> 1, h = l & 1, ll = l & 31;
    const float bu_f = bu[f], bcm_f = bcm[f];
    const size_t rb = ((size_t)e * FF + f) * FF + h * 16;

    // neighbor bitmasks of node i (bit k of mlo/mhi = adj[i][k]/adj[i][k+64])
    const unsigned long long mlo = __ballot(adj[i * NN + l] != 0);
    const unsigned long long mhi = __ballot(adj[i * NN + 64 + l] != 0);

    // on-the-fly sin_t[i] and rout_t[i] (vector layout: lane holds comp ll)
    float sinv = 0.f, routv = 0.f;
    {
        unsigned long long m = mlo;
        while (m) {
            const int k = __ffsll(m) - 1; m &= m - 1;
            sinv  += M_in[((size_t)k * NN + i) * FF + ll];
            routv += RM_in[((size_t)i * NN + k) * FF + ll];
        }
        m = mhi;
        while (m) {
            const int k = __ffsll(m) - 1 + 64; m &= m - 1;
            sinv  += M_in[((size_t)k * NN + i) * FF + ll];
            routv += RM_in[((size_t)i * NN + k) * FF + ll];
        }
    }

    const float prevv = sinv - M_in[((size_t)j * NN + i) * FF + ll];
    const float4* __restrict__ up = (const float4*)(Uu + rb);
    const float4 u0 = up[0], u1 = up[1], u2 = up[2], u3 = up[3];
    float aP = 0.f;
    {
        const int g0 = h * 16;
        DOT4(aP, u0, prevv, g0 + 0)
        DOT4(aP, u1, prevv, g0 + 4)
        DOT4(aP, u2, prevv, g0 + 8)
        DOT4(aP, u3, prevv, g0 + 12)
    }
    aP += __shfl_xor(aP, 1);
    const float wux_f = WUX[(size_t)e * FF + f];
    const float z = sig_(wux_f + aP + bu_f);

    const float rsv = routv - RM_in[(size_t)e * FF + ll];
    const float4* __restrict__ cp = (const float4*)(Ucm + rb);
    float aC = 0.f;
    {
        const int g0 = h * 16;
        DOT4(aC, cp[0], rsv, g0 + 0)
        DOT4(aC, cp[1], rsv, g0 + 4)
        DOT4(aC, cp[2], rsv, g0 + 8)
        DOT4(aC, cp[3], rsv, g0 + 12)
    }
    aC += __shfl_xor(aC, 1);
    const float cmv = tanhf(WCMX[(size_t)e * FF + f] + aC + bcm_f);

    const float prev_f = __shfl(prevv, f);
    const float m_pair = (1.f - z) * prev_f + z * cmv;
    const float mv = __shfl(m_pair, 2 * ll);
    if (l < 32) M_out[(size_t)e * FF + ll] = mv;

    float aR = 0.f;
    {
        const int g0 = h * 16;
        DOT4(aR, u0, mv, g0 + 0)
        DOT4(aR, u1, mv, g0 + 4)
        DOT4(aR, u2, mv, g0 + 8)
        DOT4(aR, u3, mv, g0 + 12)
    }
    aR += __shfl_xor(aR, 1);
    const float rm_pair = sig_(wux_f + aR + bu_f) * m_pair;
    const float rmv = __shfl(rm_pair, 2 * ll);
    if (l < 32) RM_out[(size_t)e * FF + ll] = rmv;
}

// ---------------------------------------------------------------------------
// Step 4 + out_sum + final encode, fused. Block = node i (256 thr = 4 waves).
// sin4/rout4 computed per wave from neighbor rows (registers, no LDS sync);
// waves split the node's edges round-robin; out_sum via one LDS reduce.
// No r-lookahead needed in the last step.
// ---------------------------------------------------------------------------
__global__ __launch_bounds__(256) void k_last(
        const int* __restrict__ adj, const float* __restrict__ x,
        const float* __restrict__ Uu, const float* __restrict__ Ucm,
        const float* __restrict__ bu, const float* __restrict__ bcm,
        const float* __restrict__ WUX, const float* __restrict__ WCMX,
        const float* __restrict__ M_in, const float* __restrict__ RM_in,
        const float* __restrict__ Unf, const float* __restrict__ Unm,
        float* __restrict__ out) {
    __shared__ float opp[4][FF];
    const int i = blockIdx.x;
    const int t = threadIdx.x;
    const int wv = t >> 6, l = t & 63;
    const int f = l >> 1, h = l & 1, ll = l & 31;
    const float bu_f = bu[f], bcm_f = bcm[f];

    const unsigned long long mlo = __ballot(adj[i * NN + l] != 0);
    const unsigned long long mhi = __ballot(adj[i * NN + 64 + l] != 0);

    float sinv = 0.f, routv = 0.f;
    {
        unsigned long long m = mlo;
        while (m) {
            const int k = __ffsll(m) - 1; m &= m - 1;
            sinv  += M_in[((size_t)k * NN + i) * FF + ll];
            routv += RM_in[((size_t)i * NN + k) * FF + ll];
        }
        m = mhi;
        while (m) {
            const int k = __ffsll(m) - 1 + 64; m &= m - 1;
            sinv  += M_in[((size_t)k * NN + i) * FF + ll];
            routv += RM_in[((size_t)i * NN + k) * FF + ll];
        }
    }

    float osv = 0.f;
    int idx = 0;
    unsigned long long m = mlo;
#pragma unroll 1
    for (int half = 0; half < 2; ++half) {
        while (m) {
            const int k = __ffsll(m) - 1 + half * 64; m &= m - 1;
            if ((idx++ & 3) != wv) continue;
            const int j = k;
            const size_t e = (size_t)i * NN + j;
            const size_t rb = (e * FF + f) * FF + h * 16;
            const float prevv = sinv - M_in[((size_t)j * NN + i) * FF + ll];
            const float4* __restrict__ up = (const float4*)(Uu + rb);
            float aP = 0.f;
            {
                const int g0 = h * 16;
                DOT4(aP, up[0], prevv, g0 + 0)
                DOT4(aP, up[1], prevv, g0 + 4)
                DOT4(aP, up[2], prevv, g0 + 8)
                DOT4(aP, up[3], prevv, g0 + 12)
            }
            aP += __shfl_xor(aP, 1);
            const float z = sig_(WUX[e * FF + f] + aP + bu_f);

            const float rsv = routv - RM_in[e * FF + ll];
            const float4* __restrict__ cp = (const float4*)(Ucm + rb);
            float aC = 0.f;
            {
                const int g0 = h * 16;
                DOT4(aC, cp[0], rsv, g0 + 0)
                DOT4(aC, cp[1], rsv, g0 + 4)
                DOT4(aC, cp[2], rsv, g0 + 8)
                DOT4(aC, cp[3], rsv, g0 + 12)
            }
            aC += __shfl_xor(aC, 1);
            const float cmv = tanhf(WCMX[e * FF + f] + aC + bcm_f);

            const float prev_f = __shfl(prevv, f);
            const float m_pair = (1.f - z) * prev_f + z * cmv;
            osv += __shfl(m_pair, 2 * ll);       // vector-layout accumulate
        }
        m = mhi;
    }

    if (l < 32) opp[wv][ll] = osv;
    __syncthreads();
    if (t < 64) {
        float os = 0.f;
#pragma unroll
        for (int g = 0; g < 4; ++g) os += opp[g][ll];
        const float xv = x[i * FF + ll];
        const size_t rb = ((size_t)i * FF + f) * FF + h * 16;
        const float4* __restrict__ fp = (const float4*)(Unf + rb);
        const float4* __restrict__ mp = (const float4*)(Unm + rb);
        float a = 0.f;
#pragma unroll
        for (int q = 0; q < 4; ++q) {
            const float4 f4 = fp[q], m4 = mp[q];
            const int g0 = h * 16 + q * 4;
            DOT4(a, f4, xv, g0)
            DOT4(a, m4, os, g0)
        }
        a += __shfl_xor(a, 1);
        if (h == 0) out[i * FF + f] = fmaxf(a, 0.f);
    }
}

extern "C" void kernel_launch(void* const* d_in, const int* in_sizes, int n_in,
                              void* d_out, int out_size, void* d_ws, size_t ws_size,
                              hipStream_t stream) {
    const float* x   = (const float*)d_in[0];
    const int*   adj = (const int*)d_in[1];
    const float* Wu  = (const float*)d_in[2];
    const float* Uu  = (const float*)d_in[3];
    const float* Wcm = (const float*)d_in[4];
    const float* Ucm = (const float*)d_in[5];
    const float* bu  = (const float*)d_in[6];
    const float* bcm = (const float*)d_in[7];
    const float* Unf = (const float*)d_in[8];
    const float* Unm = (const float*)d_in[9];
    float* out = (float*)d_out;

    const size_t EF = (size_t)NN * NN * FF;  // 524288 floats per dense [N,N,F]
    float* p    = (float*)d_ws;
    float* MA   = p; p += EF;
    float* MB   = p; p += EF;
    float* RMA  = p; p += EF;
    float* RMB  = p; p += EF;
    float* WUX  = p; p += EF;
    float* WCMX = p; p += EF;
    // ws use: 12 MiB. No zero-init needed anywhere: every buffer's edge rows
    // are written by the producing kernel before any consumer reads them,
    // and non-edge rows are never read (neighbor-mask walks only).

    // t=0: write MA (=M1), RMA (=RM1)
    k_step0<<<EG, 256, 0, stream>>>(adj, x, Wu, Wcm, Uu, bu, bcm,
                                    WUX, WCMX, MA, RMA);
    // t=1: MA->MB, RMA->RMB   (M2, RM2)
    k_step<<<EG, 256, 0, stream>>>(adj, Uu, Ucm, bu, bcm, WUX, WCMX,
                                   MA, MB, RMA, RMB);
    // t=2: MB->MA, RMB->RMA   (M3, RM3)
    k_step<<<EG, 256, 0, stream>>>(adj, Uu, Ucm, bu, bcm, WUX, WCMX,
                                   MB, MA, RMB, RMA);
    // t=3: MA->MB, RMA->RMB   (M4, RM4)
    k_step<<<EG, 256, 0, stream>>>(adj, Uu, Ucm, bu, bcm, WUX, WCMX,
                                   MA, MB, RMA, RMB);
    // t=4 (last) + out_sum + encode: reads MB, RMB
    k_last<<<NN, 256, 0, stream>>>(adj, x, Uu, Ucm, bu, bcm, WUX, WCMX,
                                   MB, RMB, Unf, Unm, out);
}

// Round 13
// 54.044 us; speedup vs baseline: 1.5464x; 1.5464x over previous
//
#include <hip/hip_runtime.h>
#include <math.h>

#define NN 128
#define FF 32
#define NF (NN * FF)
#define NBLK 896               // 3584 wave slots >= E (~3372), grid-stride

__device__ __forceinline__ float sig_(float v) { return 1.f / (1.f + expf(-v)); }

// acc += u4 . vec[g0..g0+3]  (vec in vector layout: lane v holds vec[v&31])
#define DOT4(acc, u4, vec, g0)                                         \
    acc += u4.x * __shfl(vec, (g0) + 0) + u4.y * __shfl(vec, (g0) + 1) \
         + u4.z * __shfl(vec, (g0) + 2) + u4.w * __shfl(vec, (g0) + 3);

// ---------------------------------------------------------------------------
// Prep (129 blocks): block 0 builds the compact ascending elist + per-row
// offsets (meta[0]=E, meta[1+i]=row_start[i], meta[129]=E); blocks 1..128
// zero the 8 accumulators (sin1..4, rout1..4) in parallel.
// ---------------------------------------------------------------------------
__global__ __launch_bounds__(256) void k_prep(
        const int* __restrict__ adj, float* __restrict__ acc,
        int* __restrict__ elist, int* __restrict__ meta) {
    const int bid = blockIdx.x, t = threadIdx.x;
    const int wv = t >> 6, l = t & 63;
    if (bid == 0) {
        // thread t owns 64 adjacency cells [t*64, t*64+64) = half of row t/2
        const int4* __restrict__ ap = (const int4*)(adj + t * 64);
        unsigned long long fl = 0ull;
#pragma unroll
        for (int q = 0; q < 16; ++q) {
            const int4 v = ap[q];
            if (v.x) fl |= 1ull << (q * 4 + 0);
            if (v.y) fl |= 1ull << (q * 4 + 1);
            if (v.z) fl |= 1ull << (q * 4 + 2);
            if (v.w) fl |= 1ull << (q * 4 + 3);
        }
        const int cnt = __popcll(fl);
        int inc = cnt;                         // inclusive scan within wave
#pragma unroll
        for (int d = 1; d < 64; d <<= 1) {
            const int n = __shfl_up(inc, d);
            if (l >= d) inc += n;
        }
        __shared__ int wt[4];
        if (l == 63) wt[wv] = inc;
        __syncthreads();
        int wb = 0;
#pragma unroll
        for (int g = 0; g < 4; ++g)
            if (g < wv) wb += wt[g];
        const int excl = wb + inc - cnt;       // exclusive prefix over 256 thr
        if ((t & 1) == 0) meta[1 + (t >> 1)] = excl;
        if (t == 255) { meta[0] = excl + cnt; meta[129] = excl + cnt; }
        int off = excl;
#pragma unroll
        for (int k = 0; k < 64; ++k)
            if ((fl >> k) & 1ull) elist[off++] = t * 64 + k;
    } else {
        acc[(bid - 1) * 256 + t] = 0.f;        // 128 blocks x 256 = 8*NF words
    }
}

// ---------------------------------------------------------------------------
// Step 0 (messages == 0). One wave per edge e=(i,j) via compact elist:
//   wux = Wu[e]@x_i, wcmx = Wcm[e]@x_i (persisted); M1 = sig(wux+bu)*tanh(wcmx+bcm)
//   sin1[j] += M1; lookahead r1 = sig(wux + Uu[e]@M1 + bu); RM = r1*M1;
//   rout1[i] += RM.
// Lane l: f = l>>1 (output row), h = l&1 (16-col half), ll = l&31 (vector).
// ---------------------------------------------------------------------------
__global__ __launch_bounds__(256) void k_step0(
        const int* __restrict__ elist, const int* __restrict__ meta,
        const float* __restrict__ x,
        const float* __restrict__ Wu, const float* __restrict__ Wcm,
        const float* __restrict__ Uu,
        const float* __restrict__ bu, const float* __restrict__ bcm,
        float* __restrict__ WUX, float* __restrict__ WCMX,
        float* __restrict__ M1, float* __restrict__ RM,
        float* __restrict__ sin1, float* __restrict__ rout1) {
    const int E = meta[0];
    const int gw = blockIdx.x * 4 + (threadIdx.x >> 6);
    const int l = threadIdx.x & 63;
    const int f = l >> 1, h = l & 1, ll = l & 31;
    const float bu_f = bu[f], bcm_f = bcm[f];
    for (int slot = gw; slot < E; slot += NBLK * 4) {
        const int e = elist[slot];
        const int i = e >> 7, j = e & 127;
        const size_t rb = ((size_t)e * FF + f) * FF + h * 16;
        const float xv = x[i * FF + ll];
        const float4* __restrict__ wp = (const float4*)(Wu + rb);
        const float4* __restrict__ cp = (const float4*)(Wcm + rb);
        float a0 = 0.f, a1 = 0.f;
#pragma unroll
        for (int q = 0; q < 4; ++q) {
            const float4 w4 = wp[q], c4 = cp[q];
            const int g0 = h * 16 + q * 4;
            DOT4(a0, w4, xv, g0)
            DOT4(a1, c4, xv, g0)
        }
        a0 += __shfl_xor(a0, 1);
        a1 += __shfl_xor(a1, 1);
        if (h == 0) {
            WUX[(size_t)e * FF + f] = a0;
            WCMX[(size_t)e * FF + f] = a1;
        }
        const float m_pair = sig_(a0 + bu_f) * tanhf(a1 + bcm_f);
        const float mv = __shfl(m_pair, 2 * ll);     // vector layout
        if (l < 32) {
            M1[(size_t)e * FF + ll] = mv;
            atomicAdd(&sin1[j * FF + ll], mv);
        }
        const float4* __restrict__ up = (const float4*)(Uu + rb);
        float aR = 0.f;
#pragma unroll
        for (int q = 0; q < 4; ++q) {
            const float4 u4 = up[q];
            const int g0 = h * 16 + q * 4;
            DOT4(aR, u4, mv, g0)
        }
        aR += __shfl_xor(aR, 1);
        const float rm_pair = sig_(a0 + aR + bu_f) * m_pair;
        const float rmv = __shfl(rm_pair, 2 * ll);
        if (l < 32) {
            RM[(size_t)e * FF + ll] = rmv;
            atomicAdd(&rout1[i * FF + ll], rmv);
        }
    }
}

// ---------------------------------------------------------------------------
// Steps 1..3. One wave per edge via compact elist (round-5 proven math):
//   prev = sin_t[i] - M_in[j,i]
//   z = sig(WUX + Uu[e]@prev + bu)    (Uu row register-cached, reused for r')
//   rs = rout_t[i] - RM[e];  cm = tanh(WCMX + Ucm[e]@rs + bcm)
//   mnew = (1-z)*prev + z*cm -> M_out, sin_next[j] +=
//   r' = sig(WUX + Uu[e]@mnew + bu);  RM[e] = r'*mnew;  rout_next[i] +=
// ---------------------------------------------------------------------------
__global__ __launch_bounds__(256) void k_step(
        const int* __restrict__ elist, const int* __restrict__ meta,
        const float* __restrict__ Uu, const float* __restrict__ Ucm,
        const float* __restrict__ bu, const float* __restrict__ bcm,
        const float* __restrict__ WUX, const float* __restrict__ WCMX,
        const float* __restrict__ M_in, float* __restrict__ M_out,
        float* __restrict__ RM,
        const float* __restrict__ sin_t, const float* __restrict__ rout_t,
        float* __restrict__ sin_n, float* __restrict__ rout_n) {
    const int E = meta[0];
    const int gw = blockIdx.x * 4 + (threadIdx.x >> 6);
    const int l = threadIdx.x & 63;
    const int f = l >> 1, h = l & 1, ll = l & 31;
    const float bu_f = bu[f], bcm_f = bcm[f];
    for (int slot = gw; slot < E; slot += NBLK * 4) {
        const int e = elist[slot];
        const int i = e >> 7, j = e & 127;
        const size_t rb = ((size_t)e * FF + f) * FF + h * 16;

        const float prevv = sin_t[i * FF + ll] - M_in[((size_t)j * NN + i) * FF + ll];
        const float4* __restrict__ up = (const float4*)(Uu + rb);
        const float4 u0 = up[0], u1 = up[1], u2 = up[2], u3 = up[3];
        float aP = 0.f;
        {
            const int g0 = h * 16;
            DOT4(aP, u0, prevv, g0 + 0)
            DOT4(aP, u1, prevv, g0 + 4)
            DOT4(aP, u2, prevv, g0 + 8)
            DOT4(aP, u3, prevv, g0 + 12)
        }
        aP += __shfl_xor(aP, 1);
        const float wux_f = WUX[(size_t)e * FF + f];
        const float z = sig_(wux_f + aP + bu_f);

        const float rsv = rout_t[i * FF + ll] - RM[(size_t)e * FF + ll];
        const float4* __restrict__ cp = (const float4*)(Ucm + rb);
        float aC = 0.f;
        {
            const int g0 = h * 16;
            DOT4(aC, cp[0], rsv, g0 + 0)
            DOT4(aC, cp[1], rsv, g0 + 4)
            DOT4(aC, cp[2], rsv, g0 + 8)
            DOT4(aC, cp[3], rsv, g0 + 12)
        }
        aC += __shfl_xor(aC, 1);
        const float cmv = tanhf(WCMX[(size_t)e * FF + f] + aC + bcm_f);

        const float prev_f = __shfl(prevv, f);
        const float m_pair = (1.f - z) * prev_f + z * cmv;
        const float mv = __shfl(m_pair, 2 * ll);
        if (l < 32) {
            M_out[(size_t)e * FF + ll] = mv;
            atomicAdd(&sin_n[j * FF + ll], mv);
        }
        float aR = 0.f;
        {
            const int g0 = h * 16;
            DOT4(aR, u0, mv, g0 + 0)
            DOT4(aR, u1, mv, g0 + 4)
            DOT4(aR, u2, mv, g0 + 8)
            DOT4(aR, u3, mv, g0 + 12)
        }
        aR += __shfl_xor(aR, 1);
        const float rm_pair = sig_(wux_f + aR + bu_f) * m_pair;
        const float rmv = __shfl(rm_pair, 2 * ll);
        if (l < 32) {
            RM[(size_t)e * FF + ll] = rmv;
            atomicAdd(&rout_n[i * FF + ll], rmv);
        }
    }
}

// ---------------------------------------------------------------------------
// Step 4 + out_sum + final encode, fused. Block = node i (256 thr, 4 waves);
// node i's edges are contiguous in elist [meta[1+i], meta[2+i]). out_sum is
// block-local (one LDS reduce) -> no atomics, no separate final dispatch.
// No r-lookahead needed in the last step.
// ---------------------------------------------------------------------------
__global__ __launch_bounds__(256) void k_last(
        const int* __restrict__ elist, const int* __restrict__ meta,
        const float* __restrict__ x,
        const float* __restrict__ Uu, const float* __restrict__ Ucm,
        const float* __restrict__ bu, const float* __restrict__ bcm,
        const float* __restrict__ WUX, const float* __restrict__ WCMX,
        const float* __restrict__ M_in, const float* __restrict__ RM,
        const float* __restrict__ sin4, const float* __restrict__ rout4,
        const float* __restrict__ Unf, const float* __restrict__ Unm,
        float* __restrict__ out) {
    __shared__ float opp[4][FF];
    const int i = blockIdx.x, t = threadIdx.x;
    const int wv = t >> 6, l = t & 63;
    const int f = l >> 1, h = l & 1, ll = l & 31;
    const int rs = meta[1 + i], re = meta[2 + i];
    const float bu_f = bu[f], bcm_f = bcm[f];
    const float sinv  = sin4[i * FF + ll];
    const float routv = rout4[i * FF + ll];
    float osv = 0.f;
    for (int s = rs + wv; s < re; s += 4) {
        const int e = elist[s];
        const int j = e & 127;
        const size_t rb = ((size_t)e * FF + f) * FF + h * 16;
        const float prevv = sinv - M_in[((size_t)j * NN + i) * FF + ll];
        const float4* __restrict__ up = (const float4*)(Uu + rb);
        float aP = 0.f;
        {
            const int g0 = h * 16;
            DOT4(aP, up[0], prevv, g0 + 0)
            DOT4(aP, up[1], prevv, g0 + 4)
            DOT4(aP, up[2], prevv, g0 + 8)
            DOT4(aP, up[3], prevv, g0 + 12)
        }
        aP += __shfl_xor(aP, 1);
        const float z = sig_(WUX[(size_t)e * FF + f] + aP + bu_f);

        const float rsv = routv - RM[(size_t)e * FF + ll];
        const float4* __restrict__ cp = (const float4*)(Ucm + rb);
        float aC = 0.f;
        {
            const int g0 = h * 16;
            DOT4(aC, cp[0], rsv, g0 + 0)
            DOT4(aC, cp[1], rsv, g0 + 4)
            DOT4(aC, cp[2], rsv, g0 + 8)
            DOT4(aC, cp[3], rsv, g0 + 12)
        }
        aC += __shfl_xor(aC, 1);
        const float cmv = tanhf(WCMX[(size_t)e * FF + f] + aC + bcm_f);

        const float prev_f = __shfl(prevv, f);
        const float m_pair = (1.f - z) * prev_f + z * cmv;
        osv += __shfl(m_pair, 2 * ll);           // vector-layout accumulate
    }
    if (l < 32) opp[wv][ll] = osv;
    __syncthreads();
    if (t < 64) {
        float os = 0.f;
#pragma unroll
        for (int g = 0; g < 4; ++g) os += opp[g][ll];
        const float xv = x[i * FF + ll];
        const size_t rb = ((size_t)i * FF + f) * FF + h * 16;
        const float4* __restrict__ fp = (const float4*)(Unf + rb);
        const float4* __restrict__ mp = (const float4*)(Unm + rb);
        float a = 0.f;
#pragma unroll
        for (int q = 0; q < 4; ++q) {
            const float4 f4 = fp[q], m4 = mp[q];
            const int g0 = h * 16 + q * 4;
            DOT4(a, f4, xv, g0)
            DOT4(a, m4, os, g0)
        }
        a += __shfl_xor(a, 1);
        if (h == 0) out[i * FF + f] = fmaxf(a, 0.f);
    }
}

extern "C" void kernel_launch(void* const* d_in, const int* in_sizes, int n_in,
                              void* d_out, int out_size, void* d_ws, size_t ws_size,
                              hipStream_t stream) {
    const float* x   = (const float*)d_in[0];
    const int*   adj = (const int*)d_in[1];
    const float* Wu  = (const float*)d_in[2];
    const float* Uu  = (const float*)d_in[3];
    const float* Wcm = (const float*)d_in[4];
    const float* Ucm = (const float*)d_in[5];
    const float* bu  = (const float*)d_in[6];
    const float* bcm = (const float*)d_in[7];
    const float* Unf = (const float*)d_in[8];
    const float* Unm = (const float*)d_in[9];
    float* out = (float*)d_out;

    const size_t EF = (size_t)NN * NN * FF;  // 524288 floats per dense [N,N,F]
    float* p    = (float*)d_ws;
    float* MA   = p; p += EF;
    float* MB   = p; p += EF;
    float* WUX  = p; p += EF;
    float* WCMX = p; p += EF;
    float* RM   = p; p += EF;
    float* acc  = p; p += 8 * NF;            // sin1..4, rout1..4 (contiguous)
    int* elist  = (int*)p;
    int* meta   = elist + NN * NN;           // meta[0]=E, meta[1..129]=row starts
    float* sinb[4]  = {acc, acc + NF, acc + 2 * NF, acc + 3 * NF};
    float* routb[4] = {acc + 4 * NF, acc + 5 * NF, acc + 6 * NF, acc + 7 * NF};
    // ws use: ~10.2 MiB

    // 6 dispatches, all parallel. No memsets, no host sync, no atom拿 races:
    // each kernel's reads are fully produced by the previous dispatch.
    k_prep<<<129, 256, 0, stream>>>(adj, acc, elist, meta);
    k_step0<<<NBLK, 256, 0, stream>>>(elist, meta, x, Wu, Wcm, Uu, bu, bcm,
                                      WUX, WCMX, MA, RM, sinb[0], routb[0]);
    // t=1: MA->MB ; t=2: MB->MA ; t=3: MA->MB ; t=4 (k_last): reads MB
    k_step<<<NBLK, 256, 0, stream>>>(elist, meta, Uu, Ucm, bu, bcm, WUX, WCMX,
                                     MA, MB, RM, sinb[0], routb[0],
                                     sinb[1], routb[1]);
    k_step<<<NBLK, 256, 0, stream>>>(elist, meta, Uu, Ucm, bu, bcm, WUX, WCMX,
                                     MB, MA, RM, sinb[1], routb[1],
                                     sinb[2], routb[2]);
    k_step<<<NBLK, 256, 0, stream>>>(elist, meta, Uu, Ucm, bu, bcm, WUX, WCMX,
                                     MA, MB, RM, sinb[2], routb[2],
                                     sinb[3], routb[3]);
    k_last<<<NN, 256, 0, stream>>>(elist, meta, x, Uu, Ucm, bu, bcm,
                                   WUX, WCMX, MB, RM, sinb[3], routb[3],
                                   Unf, Unm, out);
}

// Round 14
// 46.514 us; speedup vs baseline: 1.7968x; 1.1619x over previous
//
#include <hip/hip_runtime.h>
#include <math.h>

#define NN 128
#define FF 32
#define TT 5

__device__ __forceinline__ float sig_(float v) { return 1.f / (1.f + expf(-v)); }

// acc += u4 . vec[g0..g0+3]  (vec held in vector layout: lane v has vec[v&31])
#define DOT4(acc, u4, vec, g0)                                        \
    acc += u4.x * __shfl(vec, (g0) + 0) + u4.y * __shfl(vec, (g0) + 1) \
         + u4.z * __shfl(vec, (g0) + 2) + u4.w * __shfl(vec, (g0) + 3);

// ---------------------------------------------------------------------------
// Zero the 9 small accumulators (sin1..4, rout1..4, outsum): 9*4096 floats.
// ---------------------------------------------------------------------------
__global__ void k_zero(float* __restrict__ z) {
    z[blockIdx.x * 256 + threadIdx.x] = 0.f;
}

// ---------------------------------------------------------------------------
// Iteration 0 (messages == 0). Per directed edge e=(i,j), one wave:
//   wux = Wu[e]@x_i, wcmx = Wcm[e]@x_i  (persisted for all steps)
//   M1[e] = sig(wux+bu) * tanh(wcmx+bcm)          (prev=0, reset_sum=0)
//   sin1[j] += M1[e]
//   r1 = sig(wux + Uu[e]@M1[e] + bu); RM[e] = r1*M1[e]; rout1[i] += RM[e]
// Lane map: f = l>>1 (output row), h = l&1 (16-col half); ll = l&31 (vector).
// ---------------------------------------------------------------------------
__global__ __launch_bounds__(256) void k_step0(
        const int* __restrict__ adj, const float* __restrict__ x,
        const float* __restrict__ Wu, const float* __restrict__ Wcm,
        const float* __restrict__ Uu,
        const float* __restrict__ bu, const float* __restrict__ bcm,
        float* __restrict__ WUX, float* __restrict__ WCMX,
        float* __restrict__ M1, float* __restrict__ RM,
        float* __restrict__ sin1, float* __restrict__ rout1) {
    const int e = blockIdx.x * 4 + (threadIdx.x >> 6);
    if (!adj[e]) return;
    const int l = threadIdx.x & 63;
    const int i = e >> 7, j = e & 127;
    const int f = l >> 1, h = l & 1, ll = l & 31;
    const float xv = x[i * FF + ll];
    const size_t rb = ((size_t)e * FF + f) * FF + h * 16;
    const float4* __restrict__ wr = (const float4*)(Wu + rb);
    const float4* __restrict__ cr = (const float4*)(Wcm + rb);
    float a0 = 0.f, a1 = 0.f;
#pragma unroll
    for (int q = 0; q < 4; ++q) {
        const float4 w4 = wr[q], c4 = cr[q];
        const int g0 = h * 16 + q * 4;
        DOT4(a0, w4, xv, g0)
        DOT4(a1, c4, xv, g0)
    }
    a0 += __shfl_xor(a0, 1);
    a1 += __shfl_xor(a1, 1);
    const float bu_f = bu[f], bcm_f = bcm[f];
    const float m_pair = sig_(a0 + bu_f) * tanhf(a1 + bcm_f);
    if (h == 0) {
        WUX[(size_t)e * FF + f] = a0;
        WCMX[(size_t)e * FF + f] = a1;
    }
    const float mv = __shfl(m_pair, 2 * ll);   // vector layout
    if (l < 32) {
        M1[(size_t)e * FF + ll] = mv;
        atomicAdd(&sin1[j * FF + ll], mv);
    }
    // r for iteration 1
    const float4* __restrict__ ur = (const float4*)(Uu + rb);
    float aR = 0.f;
#pragma unroll
    for (int q = 0; q < 4; ++q) {
        const float4 u4 = ur[q];
        const int g0 = h * 16 + q * 4;
        DOT4(aR, u4, mv, g0)
    }
    aR += __shfl_xor(aR, 1);
    const float rm_pair = sig_(a0 + aR + bu_f) * m_pair;
    const float rmv = __shfl(rm_pair, 2 * ll);
    if (l < 32) {
        RM[(size_t)e * FF + ll] = rmv;
        atomicAdd(&rout1[i * FF + ll], rmv);
    }
}

// ---------------------------------------------------------------------------
// Iteration t (1..4). Per edge e=(i,j), one wave:
//   prev = sin_t[i] - M_in[j,i]
//   z  = sig(WUX + Uu[e]@prev + bu)            (Uu row cached in registers)
//   rs = rout_t[i] - RM[e]
//   cm = tanh(WCMX + Ucm[e]@rs + bcm)
//   mnew = (1-z)*prev + z*cm
//   LAST:   outsum[i] += mnew
//   !LAST:  M_out[e] = mnew; sin_next[j] += mnew;
//           r' = sig(WUX + Uu[e]@mnew + bu); RM[e] = r'*mnew; rout_next[i] += .
// ---------------------------------------------------------------------------
template <int LAST>
__global__ __launch_bounds__(256) void k_step(
        const int* __restrict__ adj,
        const float* __restrict__ Uu, const float* __restrict__ Ucm,
        const float* __restrict__ bu, const float* __restrict__ bcm,
        const float* __restrict__ WUX, const float* __restrict__ WCMX,
        const float* __restrict__ M_in, float* __restrict__ M_out,
        float* __restrict__ RM,
        const float* __restrict__ sin_t, const float* __restrict__ rout_t,
        float* __restrict__ sin_next, float* __restrict__ rout_next,
        float* __restrict__ outsum) {
    const int e = blockIdx.x * 4 + (threadIdx.x >> 6);
    if (!adj[e]) return;
    const int l = threadIdx.x & 63;
    const int i = e >> 7, j = e & 127;
    const int f = l >> 1, h = l & 1, ll = l & 31;
    const size_t rb = ((size_t)e * FF + f) * FF + h * 16;

    const float prevv = sin_t[i * FF + ll] - M_in[((size_t)j * NN + i) * FF + ll];
    const float4* __restrict__ ur = (const float4*)(Uu + rb);
    const float4 u0 = ur[0], u1 = ur[1], u2 = ur[2], u3 = ur[3];
    float aP = 0.f;
    {
        const int g0 = h * 16;
        DOT4(aP, u0, prevv, g0 + 0)
        DOT4(aP, u1, prevv, g0 + 4)
        DOT4(aP, u2, prevv, g0 + 8)
        DOT4(aP, u3, prevv, g0 + 12)
    }
    aP += __shfl_xor(aP, 1);
    const float bu_f = bu[f];
    const float wux_f = WUX[(size_t)e * FF + f];
    const float z = sig_(wux_f + aP + bu_f);

    const float rsv = rout_t[i * FF + ll] - RM[(size_t)e * FF + ll];
    const float4* __restrict__ crp = (const float4*)(Ucm + rb);
    float aC = 0.f;
    {
        const int g0 = h * 16;
        DOT4(aC, crp[0], rsv, g0 + 0)
        DOT4(aC, crp[1], rsv, g0 + 4)
        DOT4(aC, crp[2], rsv, g0 + 8)
        DOT4(aC, crp[3], rsv, g0 + 12)
    }
    aC += __shfl_xor(aC, 1);
    const float cmv = tanhf(WCMX[(size_t)e * FF + f] + aC + bcm[f]);

    const float prev_f = __shfl(prevv, f);
    const float m_pair = (1.f - z) * prev_f + z * cmv;
    const float mv = __shfl(m_pair, 2 * ll);   // vector layout

    if (LAST) {
        if (l < 32) atomicAdd(&outsum[i * FF + ll], mv);
    } else {
        if (l < 32) {
            M_out[(size_t)e * FF + ll] = mv;
            atomicAdd(&sin_next[j * FF + ll], mv);
        }
        float aR = 0.f;
        {
            const int g0 = h * 16;
            DOT4(aR, u0, mv, g0 + 0)
            DOT4(aR, u1, mv, g0 + 4)
            DOT4(aR, u2, mv, g0 + 8)
            DOT4(aR, u3, mv, g0 + 12)
        }
        aR += __shfl_xor(aR, 1);
        const float rm_pair = sig_(wux_f + aR + bu_f) * m_pair;
        const float rmv = __shfl(rm_pair, 2 * ll);
        if (l < 32) {
            RM[(size_t)e * FF + ll] = rmv;
            atomicAdd(&rout_next[i * FF + ll], rmv);
        }
    }
}

// ---------------------------------------------------------------------------
// Final node encoding: relu(Unf[i]@x[i] + Unm[i]@outsum[i]). One wave/node.
// ---------------------------------------------------------------------------
__global__ void k_final(const float* __restrict__ x, const float* __restrict__ outsum,
                        const float* __restrict__ Unf, const float* __restrict__ Unm,
                        float* __restrict__ out) {
    const int i = blockIdx.x;
    const int l = threadIdx.x;
    const int f = l >> 1, h = l & 1, ll = l & 31;
    const float xv = x[i * FF + ll];
    const float ov = outsum[i * FF + ll];
    const size_t rb = ((size_t)i * FF + f) * FF + h * 16;
    const float4* __restrict__ fr = (const float4*)(Unf + rb);
    const float4* __restrict__ mr = (const float4*)(Unm + rb);
    float a = 0.f;
#pragma unroll
    for (int q = 0; q < 4; ++q) {
        const float4 f4 = fr[q], m4 = mr[q];
        const int g0 = h * 16 + q * 4;
        DOT4(a, f4, xv, g0)
        DOT4(a, m4, ov, g0)
    }
    a += __shfl_xor(a, 1);
    if (h == 0) out[i * FF + f] = fmaxf(a, 0.f);
}

extern "C" void kernel_launch(void* const* d_in, const int* in_sizes, int n_in,
                              void* d_out, int out_size, void* d_ws, size_t ws_size,
                              hipStream_t stream) {
    const float* x   = (const float*)d_in[0];
    const int*   adj = (const int*)d_in[1];
    const float* Wu  = (const float*)d_in[2];
    const float* Uu  = (const float*)d_in[3];
    const float* Wcm = (const float*)d_in[4];
    const float* Ucm = (const float*)d_in[5];
    const float* bu  = (const float*)d_in[6];
    const float* bcm = (const float*)d_in[7];
    const float* Unf = (const float*)d_in[8];
    const float* Unm = (const float*)d_in[9];
    float* out = (float*)d_out;

    const size_t EF = (size_t)NN * NN * FF;  // 524288 floats per dense [N,N,F]
    const size_t NF = (size_t)NN * FF;       // 4096
    float* p    = (float*)d_ws;
    float* MA   = p; p += EF;
    float* MB   = p; p += EF;
    float* WUX  = p; p += EF;
    float* WCMX = p; p += EF;
    float* RM   = p; p += EF;
    float* acc  = p; p += 9 * NF;            // sin1..4, rout1..4, outsum
    float* sinb[4]  = {acc, acc + NF, acc + 2 * NF, acc + 3 * NF};
    float* routb[4] = {acc + 4 * NF, acc + 5 * NF, acc + 6 * NF, acc + 7 * NF};
    float* outsum   = acc + 8 * NF;
    // ws use: 10 MiB + 144 KiB

    const int EG = (NN * NN) / 4;  // 4096 blocks, 4 edge-waves each

    k_zero<<<(9 * NF) / 256, 256, 0, stream>>>(acc);
    k_step0<<<EG, 256, 0, stream>>>(adj, x, Wu, Wcm, Uu, bu, bcm,
                                    WUX, WCMX, MA, RM, sinb[0], routb[0]);
    // t=1: read MA -> write MB ; t=2: MB->MA ; t=3: MA->MB ; t=4: read MB
    k_step<0><<<EG, 256, 0, stream>>>(adj, Uu, Ucm, bu, bcm, WUX, WCMX,
                                      MA, MB, RM, sinb[0], routb[0],
                                      sinb[1], routb[1], outsum);
    k_step<0><<<EG, 256, 0, stream>>>(adj, Uu, Ucm, bu, bcm, WUX, WCMX,
                                      MB, MA, RM, sinb[1], routb[1],
                                      sinb[2], routb[2], outsum);
    k_step<0><<<EG, 256, 0, stream>>>(adj, Uu, Ucm, bu, bcm, WUX, WCMX,
                                      MA, MB, RM, sinb[2], routb[2],
                                      sinb[3], routb[3], outsum);
    k_step<1><<<EG, 256, 0, stream>>>(adj, Uu, Ucm, bu, bcm, WUX, WCMX,
                                      MB, MA, RM, sinb[3], routb[3],
                                      nullptr, nullptr, outsum);
    k_final<<<NN, 64, 0, stream>>>(x, outsum, Unf, Unm, out);
}